// Round 1
// baseline (309.545 us; speedup 1.0000x reference)
//
#include <hip/hip_runtime.h>

// GraphFilter B=16,T=64,F=64,N=128,E=2,K=4 — v6: S pre-transposed to bf16 in
// prep (once per slice, vs 3x in-chain before); chain A-frags load straight
// from global (per-wave-exclusive under n-split), sZ double-buffered ->
// 1 barrier per doMM (was 4), LDS 34.8 KB -> 4 blocks/CU co-resident.
// XCD-swizzled blockIdx so t,t+1,t+2 (sharing S^T slices) hit the same L2.
// State Z = W^T [n][o].  Per (b,t), per e:
//   Z = U3^T[t-3];  Z = U2^T[t-2] + S^T[t-2]@Z;  Z = U1^T[t-1] + S^T[t-1]@Z;
//   Y^T += U0^T[t] + S^T[t]@Z
// U_k^T[n][o] = sum_f xT[s][n][f] H[o,e,k,f].

namespace {
constexpr int B = 16, T = 64, F = 64, N = 128, E = 2, K = 4;
constexpr int SSW = 136;  // prep LDS row stride (ushorts) for S transpose
constexpr int SZW = 136;  // sZ row stride (ushorts)
}

typedef short v8s __attribute__((ext_vector_type(8)));
typedef float v4f __attribute__((ext_vector_type(4)));

__device__ inline ushort f2bf(float f) {
  union { float f; uint u; } v; v.f = f;
  uint u = v.u;
  return (ushort)((u + 0x7fffu + ((u >> 16) & 1u)) >> 16);
}

__device__ inline uint pk2(float a, float b) {
  return (uint)f2bf(a) | ((uint)f2bf(b) << 16);
}

// ---- prep ----
// blocks [0, B*T):            x fp32 [f][n] -> xT bf16 [n][f]
// blocks [B*T, B*T+32):       H -> Hb bf16 [e][k][o][f]
// blocks [B*T+32, +B*T*E):    S fp32 [m][n] -> ST bf16 [n][m]  (per (b,t,e))
__global__ __launch_bounds__(256) void gf_prep(
    const float* __restrict__ x, const float* __restrict__ S,
    const float* __restrict__ H, ushort* __restrict__ xT,
    ushort* __restrict__ Hb, ushort* __restrict__ ST) {
  __shared__ ushort sh[128 * SSW];
  const int bid = blockIdx.x;
  const int tid = threadIdx.x;
  if (bid < B * T) {
    const float* xg = x + (size_t)bid * F * N;
    ushort* Og = xT + (size_t)bid * N * F;
    #pragma unroll
    for (int it = 0; it < 4; ++it) {
      const int idx = tid + it * 256;    // (f, g)
      const int f = idx >> 4, g = idx & 15;
      const float4 v0 = *(const float4*)(xg + f * N + g * 8);
      const float4 v1 = *(const float4*)(xg + f * N + g * 8 + 4);
      uint4 wv;
      wv.x = pk2(v0.x, v0.y); wv.y = pk2(v0.z, v0.w);
      wv.z = pk2(v1.x, v1.y); wv.w = pk2(v1.z, v1.w);
      const int gp = g ^ (f >> 3);
      *(uint4*)&sh[f * 128 + gp * 8] = wv;
    }
    __syncthreads();
    if (tid < 128) {
      const int a = tid & 7, b = tid >> 3;   // a: f-grp, b: n-grp
      v8s rows[8];
      #pragma unroll
      for (int j = 0; j < 8; ++j)
        rows[j] = *(const v8s*)&sh[(8 * a + j) * 128 + ((b ^ a) * 8)];
      #pragma unroll
      for (int i = 0; i < 8; ++i) {
        uint4 wv;
        wv.x = (uint)(ushort)rows[0][i] | ((uint)(ushort)rows[1][i] << 16);
        wv.y = (uint)(ushort)rows[2][i] | ((uint)(ushort)rows[3][i] << 16);
        wv.z = (uint)(ushort)rows[4][i] | ((uint)(ushort)rows[5][i] << 16);
        wv.w = (uint)(ushort)rows[6][i] | ((uint)(ushort)rows[7][i] << 16);
        *(uint4*)(Og + (8 * b + i) * F + 8 * a) = wv;
      }
    }
  } else if (bid < B * T + 32) {
    const int hb = bid - B * T;
    const int d = (hb * 256 + tid) * 4;    // linear over [e][k][o][f]
    const int f = d & 63, o = (d >> 6) & 63, k = (d >> 12) & 3, e = (d >> 14) & 1;
    const float4 v = *(const float4*)(H + (((size_t)o * E + e) * K + k) * F + f);
    uint2 wv;
    wv.x = pk2(v.x, v.y);
    wv.y = pk2(v.z, v.w);
    *(uint2*)(Hb + d) = wv;
  } else {
    // S transpose: fp32 [m][n] -> bf16 [n][m], 3-phase XOR-swizzled LDS
    const int sid = bid - (B * T + 32);          // (b*T+t)*E + e
    const float* Sg = S + (size_t)sid * (N * N);
    ushort* Og = ST + (size_t)sid * (N * N);
    // phase1: load fp32 rows, pack bf16, store swizzled [m][n]
    #pragma unroll
    for (int half = 0; half < 2; ++half) {
      float4 r0[4], r1[4];
      #pragma unroll
      for (int it = 0; it < 4; ++it) {
        const int idx = tid + (half * 4 + it) * 256;
        const int m = idx >> 4, g = idx & 15;
        r0[it] = *(const float4*)(Sg + m * N + g * 8);
        r1[it] = *(const float4*)(Sg + m * N + g * 8 + 4);
      }
      #pragma unroll
      for (int it = 0; it < 4; ++it) {
        const int idx = tid + (half * 4 + it) * 256;
        const int m = idx >> 4, g = idx & 15;
        uint4 wv;
        wv.x = pk2(r0[it].x, r0[it].y); wv.y = pk2(r0[it].z, r0[it].w);
        wv.z = pk2(r1[it].x, r1[it].y); wv.w = pk2(r1[it].z, r1[it].w);
        *(uint4*)&sh[m * SSW + ((g ^ (m >> 3)) * 8)] = wv;
      }
    }
    __syncthreads();
    // phase2: read 8x8 blocks; phase3: write transposed [n][m] to global
    const int a = tid & 15, bg = tid >> 4;
    v8s rows[8];
    #pragma unroll
    for (int j = 0; j < 8; ++j)
      rows[j] = *(const v8s*)&sh[(8 * a + j) * SSW + ((bg ^ a) * 8)];
    #pragma unroll
    for (int i = 0; i < 8; ++i) {
      uint4 wv;
      wv.x = (uint)(ushort)rows[0][i] | ((uint)(ushort)rows[1][i] << 16);
      wv.y = (uint)(ushort)rows[2][i] | ((uint)(ushort)rows[3][i] << 16);
      wv.z = (uint)(ushort)rows[4][i] | ((uint)(ushort)rows[5][i] << 16);
      wv.w = (uint)(ushort)rows[6][i] | ((uint)(ushort)rows[7][i] << 16);
      *(uint4*)(Og + (8 * bg + i) * N + 8 * a) = wv;
    }
  }
}

// ---- fused chain: one block per (b,t); wave w owns n in [32w, 32w+32) ----
// S^T comes pre-transposed bf16 from global (A-frags per-wave-exclusive ->
// direct global->VGPR, no LDS staging). Only Z hand-off uses LDS, double-
// buffered: exactly one __syncthreads per doMM.
__global__ __launch_bounds__(256, 4) void gf_chain(
    const ushort* __restrict__ ST, const ushort* __restrict__ xT,
    const ushort* __restrict__ Hb, const float* __restrict__ bias,
    float* __restrict__ y) {
  __shared__ ushort sZ[2][64 * SZW];   // 2 x 17.4 KB: Z in B-operand layout [o][n]
  const int bid0 = blockIdx.x;
  const int bid = ((bid0 & 7) << 7) | (bid0 >> 3);  // XCD-contiguous t (1024%8==0)
  const int t = bid & (T - 1);
  const int tid = threadIdx.x, w = tid >> 6, lane = tid & 63;
  const int l15 = lane & 15, q = lane >> 4;

  v4f yacc[2][4];
  #pragma unroll
  for (int mt = 0; mt < 2; ++mt)
    #pragma unroll
    for (int ot = 0; ot < 4; ++ot) {
      yacc[mt][ot][0] = 0.f; yacc[mt][ot][1] = 0.f;
      yacc[mt][ot][2] = 0.f; yacc[mt][ot][3] = 0.f;
    }

  int pb = 0;
  for (int e = 0; e < E; ++e) {
    v4f acc[2][4];
    bool have = false;
    #pragma unroll
    for (int tap = 3; tap >= 0; --tap) {
      const int s = t - tap;
      if (s < 0) continue;
      const bool doMM = have;

      if (doMM) {
        // spill Z (in acc) -> sZ[pb] as [o][n], n contiguous
        #pragma unroll
        for (int mt = 0; mt < 2; ++mt)
          #pragma unroll
          for (int ot = 0; ot < 4; ++ot) {
            uint2 wv;
            wv.x = pk2(acc[mt][ot][0], acc[mt][ot][1]);
            wv.y = pk2(acc[mt][ot][2], acc[mt][ot][3]);
            *(uint2*)&sZ[pb][(ot * 16 + l15) * SZW + (2 * w + mt) * 16 + q * 4] = wv;
          }
      }

      // proj: tgt += U_tap^T (global xT / Hb only — independent of LDS)
      v4f (*tgt)[4] = (tap == 0) ? yacc : acc;
      if (tap != 0) {
        #pragma unroll
        for (int mt = 0; mt < 2; ++mt)
          #pragma unroll
          for (int ot = 0; ot < 4; ++ot) {
            acc[mt][ot][0] = 0.f; acc[mt][ot][1] = 0.f;
            acc[mt][ot][2] = 0.f; acc[mt][ot][3] = 0.f;
          }
      }
      {
        const ushort* xrow = xT + (size_t)(bid - tap) * (N * F);
        const ushort* hbase = Hb + (size_t)((e * K + tap) * 64) * 64;
        #pragma unroll
        for (int fk = 0; fk < 2; ++fk) {   // fk-split keeps frag liveness low
          v8s xfk[2], hfk[4];
          #pragma unroll
          for (int mt = 0; mt < 2; ++mt)
            xfk[mt] = *(const v8s*)(xrow + ((2 * w + mt) * 16 + l15) * F + fk * 32 + q * 8);
          #pragma unroll
          for (int ot = 0; ot < 4; ++ot)
            hfk[ot] = *(const v8s*)(hbase + (ot * 16 + l15) * 64 + fk * 32 + q * 8);
          #pragma unroll
          for (int mt = 0; mt < 2; ++mt)
            #pragma unroll
            for (int ot = 0; ot < 4; ++ot)
              tgt[mt][ot] = __builtin_amdgcn_mfma_f32_16x16x32_bf16(
                  xfk[mt], hfk[ot], tgt[mt][ot], 0, 0, 0);
        }
      }

      if (doMM) {
        // mm: tgt += S^T @ Z ; A-frags straight from global ST (bf16 [n][m]),
        // 1-deep pipelined over c; bz from sZ[pb].
        const ushort* STg = ST + (size_t)((bid - tap) * E + e) * (N * N);
        const ushort* sr0 = STg + ((2 * w) * 16 + l15) * N + q * 8;
        const ushort* sr1 = STg + ((2 * w + 1) * 16 + l15) * N + q * 8;
        v8s af[2][2];
        af[0][0] = *(const v8s*)sr0;
        af[0][1] = *(const v8s*)sr1;
        __syncthreads();   // spill visible (single barrier per doMM)
        #pragma unroll
        for (int c = 0; c < 4; ++c) {
          if (c < 3) {
            af[(c + 1) & 1][0] = *(const v8s*)(sr0 + (c + 1) * 32);
            af[(c + 1) & 1][1] = *(const v8s*)(sr1 + (c + 1) * 32);
          }
          v8s bz[4];
          #pragma unroll
          for (int ot = 0; ot < 4; ++ot)
            bz[ot] = *(const v8s*)&sZ[pb][(ot * 16 + l15) * SZW + c * 32 + q * 8];
          #pragma unroll
          for (int mt = 0; mt < 2; ++mt)
            #pragma unroll
            for (int ot = 0; ot < 4; ++ot)
              tgt[mt][ot] = __builtin_amdgcn_mfma_f32_16x16x32_bf16(
                  af[c & 1][mt], bz[ot], tgt[mt][ot], 0, 0, 0);
        }
        pb ^= 1;
      }
      have = true;
    }
  }

  // epilogue: y[b,t][o][n] = Y^T[n][o] + bias[o]
  float* yg = y + (size_t)bid * (F * N);
  #pragma unroll
  for (int ot = 0; ot < 4; ++ot) {
    const int o = ot * 16 + l15;
    const float bv = bias[o];
    #pragma unroll
    for (int mt = 0; mt < 2; ++mt) {
      float4 v;
      v.x = yacc[mt][ot][0] + bv; v.y = yacc[mt][ot][1] + bv;
      v.z = yacc[mt][ot][2] + bv; v.w = yacc[mt][ot][3] + bv;
      *(float4*)(yg + o * N + (2 * w + mt) * 16 + q * 4) = v;
    }
  }
}

extern "C" void kernel_launch(void* const* d_in, const int* in_sizes, int n_in,
                              void* d_out, int out_size, void* d_ws, size_t ws_size,
                              hipStream_t stream) {
  const float* x    = (const float*)d_in[0];
  const float* S    = (const float*)d_in[1];
  const float* H    = (const float*)d_in[2];
  const float* bias = (const float*)d_in[3];
  float* y = (float*)d_out;

  const size_t XTn = (size_t)B * T * N * F;        // 8.39M ushorts (16.8 MB)
  const size_t HBn = (size_t)E * K * F * F;        // 32768 ushorts
  ushort* xT = (ushort*)d_ws;
  ushort* Hb = xT + XTn;
  ushort* ST = Hb + HBn;                           // B*T*E*N*N ushorts (67 MB)

  gf_prep <<<B * T + 32 + B * T * E, 256, 0, stream>>>(x, S, H, xT, Hb, ST);
  gf_chain<<<B * T,                  256, 0, stream>>>(ST, xT, Hb, bias, y);
}

// Round 2
// 306.877 us; speedup vs baseline: 1.0087x; 1.0087x over previous
//
#include <hip/hip_runtime.h>

// GraphFilter B=16,T=64,F=64,N=128,E=2,K=4 — v7: fast prep.
// Prep transposes via 64x128 tiles (LDS 17.4 KB -> 8 blocks/CU, 100% occ
// ceiling), ONE barrier per block, all 256 threads active in every phase;
// x-transpose unified into the same path. Chain unchanged from v6:
// S pre-transposed bf16 in global, A-frags global->VGPR, sZ double-buffered,
// 1 barrier per doMM, XCD-swizzled blockIdx.
// State Z = W^T [n][o].  Per (b,t), per e:
//   Z = U3^T[t-3];  Z = U2^T[t-2] + S^T[t-2]@Z;  Z = U1^T[t-1] + S^T[t-1]@Z;
//   Y^T += U0^T[t] + S^T[t]@Z
// U_k^T[n][o] = sum_f xT[s][n][f] H[o,e,k,f].

namespace {
constexpr int B = 16, T = 64, F = 64, N = 128, E = 2, K = 4;
constexpr int SSW = 136;  // prep LDS row stride (ushorts)
constexpr int SZW = 136;  // sZ row stride (ushorts)
}

typedef short v8s __attribute__((ext_vector_type(8)));
typedef float v4f __attribute__((ext_vector_type(4)));

__device__ inline ushort f2bf(float f) {
  union { float f; uint u; } v; v.f = f;
  uint u = v.u;
  return (ushort)((u + 0x7fffu + ((u >> 16) & 1u)) >> 16);
}

__device__ inline uint pk2(float a, float b) {
  return (uint)f2bf(a) | ((uint)f2bf(b) << 16);
}

// Transpose one 64x128 fp32 tile (row stride 128) -> bf16 [128][64]
// (row stride dstride, caller pre-offsets dst to the right column base).
// One barrier. Phase1: coalesced float4 loads, pack, XOR-swizzled LDS store.
// Phase2/3: 8-row b128 reads (2-way conflict max = free), 16B global writes
// with 8 lanes covering 128 B contiguous per output row.
__device__ inline void tr64x128(const float* __restrict__ src,
                                ushort* __restrict__ dst, int dstride,
                                ushort* sh, int tid) {
  float4 r0[4], r1[4];
  #pragma unroll
  for (int it = 0; it < 4; ++it) {
    const int idx = tid + it * 256;     // (m,g): m = idx>>4 in 0..63, g = idx&15
    const int m = idx >> 4, g = idx & 15;
    r0[it] = *(const float4*)(src + m * N + g * 8);
    r1[it] = *(const float4*)(src + m * N + g * 8 + 4);
  }
  #pragma unroll
  for (int it = 0; it < 4; ++it) {
    const int idx = tid + it * 256;
    const int m = idx >> 4, g = idx & 15;
    uint4 wv;
    wv.x = pk2(r0[it].x, r0[it].y); wv.y = pk2(r0[it].z, r0[it].w);
    wv.z = pk2(r1[it].x, r1[it].y); wv.w = pk2(r1[it].z, r1[it].w);
    *(uint4*)&sh[m * SSW + ((g ^ (m >> 3)) * 8)] = wv;
  }
  __syncthreads();
  // thread -> (bb = m-grp 0..7, a = n-grp 0..15, hh = n-half 0..1)
  const int bb = tid & 7, a = (tid >> 3) & 15, hh = tid >> 7;
  v8s rows[8];
  #pragma unroll
  for (int j = 0; j < 8; ++j)
    rows[j] = *(const v8s*)&sh[(8 * bb + j) * SSW + ((a ^ bb) * 8)];
  #pragma unroll
  for (int i = 0; i < 4; ++i) {
    const int e = 4 * hh + i;           // element within n-group
    const int n = 8 * a + e;
    uint4 wv;
    wv.x = (uint)(ushort)rows[0][e] | ((uint)(ushort)rows[1][e] << 16);
    wv.y = (uint)(ushort)rows[2][e] | ((uint)(ushort)rows[3][e] << 16);
    wv.z = (uint)(ushort)rows[4][e] | ((uint)(ushort)rows[5][e] << 16);
    wv.w = (uint)(ushort)rows[6][e] | ((uint)(ushort)rows[7][e] << 16);
    *(uint4*)(dst + n * dstride + 8 * bb) = wv;
  }
}

// ---- prep ----
// blocks [0, B*T):             x fp32 [f][n] -> xT bf16 [n][f]
// blocks [B*T, B*T+32):        H -> Hb bf16 [e][k][o][f]
// blocks [B*T+32, +2*B*T*E):   S fp32 [m][n] -> ST bf16 [n][m] (64-row halves)
__global__ __launch_bounds__(256) void gf_prep(
    const float* __restrict__ x, const float* __restrict__ S,
    const float* __restrict__ H, ushort* __restrict__ xT,
    ushort* __restrict__ Hb, ushort* __restrict__ ST) {
  __shared__ ushort sh[64 * SSW];       // 17.4 KB
  const int bid = blockIdx.x;
  const int tid = threadIdx.x;
  if (bid < B * T) {
    // x slice: 64 rows (f) x 128 cols (n) -> xT [n][f], dstride F=64
    tr64x128(x + (size_t)bid * F * N, xT + (size_t)bid * N * F, F, sh, tid);
  } else if (bid < B * T + 32) {
    const int hb = bid - B * T;
    const int d = (hb * 256 + tid) * 4;    // linear over [e][k][o][f]
    const int f = d & 63, o = (d >> 6) & 63, k = (d >> 12) & 3, e = (d >> 14) & 1;
    const float4 v = *(const float4*)(H + (((size_t)o * E + e) * K + k) * F + f);
    uint2 wv;
    wv.x = pk2(v.x, v.y);
    wv.y = pk2(v.z, v.w);
    *(uint2*)(Hb + d) = wv;
  } else {
    // S tile: slice sid, m-half h: rows m in [64h, 64h+64) -> ST cols 64h..
    const int sb = bid - (B * T + 32);
    const int sid = sb >> 1, h = sb & 1;
    tr64x128(S + (size_t)sid * (N * N) + (size_t)h * 64 * N,
             ST + (size_t)sid * (N * N) + h * 64, N, sh, tid);
  }
}

// ---- fused chain: one block per (b,t); wave w owns n in [32w, 32w+32) ----
// S^T comes pre-transposed bf16 from global (A-frags per-wave-exclusive ->
// direct global->VGPR, no LDS staging). Only Z hand-off uses LDS, double-
// buffered: exactly one __syncthreads per doMM.
__global__ __launch_bounds__(256, 4) void gf_chain(
    const ushort* __restrict__ ST, const ushort* __restrict__ xT,
    const ushort* __restrict__ Hb, const float* __restrict__ bias,
    float* __restrict__ y) {
  __shared__ ushort sZ[2][64 * SZW];   // 2 x 17.4 KB: Z in B-operand layout [o][n]
  const int bid0 = blockIdx.x;
  const int bid = ((bid0 & 7) << 7) | (bid0 >> 3);  // XCD-contiguous t (1024%8==0)
  const int t = bid & (T - 1);
  const int tid = threadIdx.x, w = tid >> 6, lane = tid & 63;
  const int l15 = lane & 15, q = lane >> 4;

  v4f yacc[2][4];
  #pragma unroll
  for (int mt = 0; mt < 2; ++mt)
    #pragma unroll
    for (int ot = 0; ot < 4; ++ot) {
      yacc[mt][ot][0] = 0.f; yacc[mt][ot][1] = 0.f;
      yacc[mt][ot][2] = 0.f; yacc[mt][ot][3] = 0.f;
    }

  int pb = 0;
  for (int e = 0; e < E; ++e) {
    v4f acc[2][4];
    bool have = false;
    #pragma unroll
    for (int tap = 3; tap >= 0; --tap) {
      const int s = t - tap;
      if (s < 0) continue;
      const bool doMM = have;

      if (doMM) {
        // spill Z (in acc) -> sZ[pb] as [o][n], n contiguous
        #pragma unroll
        for (int mt = 0; mt < 2; ++mt)
          #pragma unroll
          for (int ot = 0; ot < 4; ++ot) {
            uint2 wv;
            wv.x = pk2(acc[mt][ot][0], acc[mt][ot][1]);
            wv.y = pk2(acc[mt][ot][2], acc[mt][ot][3]);
            *(uint2*)&sZ[pb][(ot * 16 + l15) * SZW + (2 * w + mt) * 16 + q * 4] = wv;
          }
      }

      // proj: tgt += U_tap^T (global xT / Hb only — independent of LDS)
      v4f (*tgt)[4] = (tap == 0) ? yacc : acc;
      if (tap != 0) {
        #pragma unroll
        for (int mt = 0; mt < 2; ++mt)
          #pragma unroll
          for (int ot = 0; ot < 4; ++ot) {
            acc[mt][ot][0] = 0.f; acc[mt][ot][1] = 0.f;
            acc[mt][ot][2] = 0.f; acc[mt][ot][3] = 0.f;
          }
      }
      {
        const ushort* xrow = xT + (size_t)(bid - tap) * (N * F);
        const ushort* hbase = Hb + (size_t)((e * K + tap) * 64) * 64;
        #pragma unroll
        for (int fk = 0; fk < 2; ++fk) {   // fk-split keeps frag liveness low
          v8s xfk[2], hfk[4];
          #pragma unroll
          for (int mt = 0; mt < 2; ++mt)
            xfk[mt] = *(const v8s*)(xrow + ((2 * w + mt) * 16 + l15) * F + fk * 32 + q * 8);
          #pragma unroll
          for (int ot = 0; ot < 4; ++ot)
            hfk[ot] = *(const v8s*)(hbase + (ot * 16 + l15) * 64 + fk * 32 + q * 8);
          #pragma unroll
          for (int mt = 0; mt < 2; ++mt)
            #pragma unroll
            for (int ot = 0; ot < 4; ++ot)
              tgt[mt][ot] = __builtin_amdgcn_mfma_f32_16x16x32_bf16(
                  xfk[mt], hfk[ot], tgt[mt][ot], 0, 0, 0);
        }
      }

      if (doMM) {
        // mm: tgt += S^T @ Z ; A-frags straight from global ST (bf16 [n][m]),
        // 1-deep pipelined over c; bz from sZ[pb].
        const ushort* STg = ST + (size_t)((bid - tap) * E + e) * (N * N);
        const ushort* sr0 = STg + ((2 * w) * 16 + l15) * N + q * 8;
        const ushort* sr1 = STg + ((2 * w + 1) * 16 + l15) * N + q * 8;
        v8s af[2][2];
        af[0][0] = *(const v8s*)sr0;
        af[0][1] = *(const v8s*)sr1;
        __syncthreads();   // spill visible (single barrier per doMM)
        #pragma unroll
        for (int c = 0; c < 4; ++c) {
          if (c < 3) {
            af[(c + 1) & 1][0] = *(const v8s*)(sr0 + (c + 1) * 32);
            af[(c + 1) & 1][1] = *(const v8s*)(sr1 + (c + 1) * 32);
          }
          v8s bz[4];
          #pragma unroll
          for (int ot = 0; ot < 4; ++ot)
            bz[ot] = *(const v8s*)&sZ[pb][(ot * 16 + l15) * SZW + c * 32 + q * 8];
          #pragma unroll
          for (int mt = 0; mt < 2; ++mt)
            #pragma unroll
            for (int ot = 0; ot < 4; ++ot)
              tgt[mt][ot] = __builtin_amdgcn_mfma_f32_16x16x32_bf16(
                  af[c & 1][mt], bz[ot], tgt[mt][ot], 0, 0, 0);
        }
        pb ^= 1;
      }
      have = true;
    }
  }

  // epilogue: y[b,t][o][n] = Y^T[n][o] + bias[o]
  float* yg = y + (size_t)bid * (F * N);
  #pragma unroll
  for (int ot = 0; ot < 4; ++ot) {
    const int o = ot * 16 + l15;
    const float bv = bias[o];
    #pragma unroll
    for (int mt = 0; mt < 2; ++mt) {
      float4 v;
      v.x = yacc[mt][ot][0] + bv; v.y = yacc[mt][ot][1] + bv;
      v.z = yacc[mt][ot][2] + bv; v.w = yacc[mt][ot][3] + bv;
      *(float4*)(yg + o * N + (2 * w + mt) * 16 + q * 4) = v;
    }
  }
}

extern "C" void kernel_launch(void* const* d_in, const int* in_sizes, int n_in,
                              void* d_out, int out_size, void* d_ws, size_t ws_size,
                              hipStream_t stream) {
  const float* x    = (const float*)d_in[0];
  const float* S    = (const float*)d_in[1];
  const float* H    = (const float*)d_in[2];
  const float* bias = (const float*)d_in[3];
  float* y = (float*)d_out;

  const size_t XTn = (size_t)B * T * N * F;        // 8.39M ushorts (16.8 MB)
  const size_t HBn = (size_t)E * K * F * F;        // 32768 ushorts
  ushort* xT = (ushort*)d_ws;
  ushort* Hb = xT + XTn;
  ushort* ST = Hb + HBn;                           // B*T*E*N*N ushorts (67 MB)

  gf_prep <<<B * T + 32 + 2 * B * T * E, 256, 0, stream>>>(x, S, H, xT, Hb, ST);
  gf_chain<<<B * T,                      256, 0, stream>>>(ST, xT, Hb, bias, y);
}